// Round 1
// baseline (3662.334 us; speedup 1.0000x reference)
//
#include <hip/hip_runtime.h>
#include <math.h>

// Problem constants (B=1 fixed)
#define S_LEN 2048
#define DMODEL 4096
#define NHQ 32
#define NHKV 8
#define HD 128
#define DQ 4096    // NHQ*HD
#define DKV 1024   // NHKV*HD

// ---------------------------------------------------------------------------
// GEMM: C[M,N] = A[M,K] * B[N,K]^T   (both row-major, K contiguous)
// 64x64 tile, BK=32, 256 threads, 4x4 micro-tile per thread.
// ---------------------------------------------------------------------------
#define TM 64
#define TN 64
#define TK 32

__global__ __launch_bounds__(256) void gemm_abt(const float* __restrict__ A,
                                                const float* __restrict__ B,
                                                float* __restrict__ C,
                                                int M, int N, int K)
{
    __shared__ __align__(16) float As[TK][TM + 4];   // [k][m], stride 68 floats (16B aligned rows)
    __shared__ __align__(16) float Bs[TK][TN + 4];

    const int tid = threadIdx.x;
    const int tx = tid & 15, ty = tid >> 4;
    const int bm = blockIdx.y * TM, bn = blockIdx.x * TN;

    float acc[4][4] = {};

    for (int k0 = 0; k0 < K; k0 += TK) {
        // Stage A,B tiles: each thread 2 float4 per operand, coalesced along K.
        #pragma unroll
        for (int l = 0; l < 2; ++l) {
            const int idx = tid + l * 256;
            const int r  = idx >> 3;          // 0..63 tile row
            const int kk = (idx & 7) << 2;    // 0..28 k offset
            const float4 va = *reinterpret_cast<const float4*>(&A[(size_t)(bm + r) * K + k0 + kk]);
            As[kk + 0][r] = va.x; As[kk + 1][r] = va.y; As[kk + 2][r] = va.z; As[kk + 3][r] = va.w;
            const float4 vb = *reinterpret_cast<const float4*>(&B[(size_t)(bn + r) * K + k0 + kk]);
            Bs[kk + 0][r] = vb.x; Bs[kk + 1][r] = vb.y; Bs[kk + 2][r] = vb.z; Bs[kk + 3][r] = vb.w;
        }
        __syncthreads();
        #pragma unroll
        for (int k = 0; k < TK; ++k) {
            const float4 a = *reinterpret_cast<const float4*>(&As[k][ty << 2]);
            const float4 b = *reinterpret_cast<const float4*>(&Bs[k][tx << 2]);
            acc[0][0] = fmaf(a.x, b.x, acc[0][0]); acc[0][1] = fmaf(a.x, b.y, acc[0][1]);
            acc[0][2] = fmaf(a.x, b.z, acc[0][2]); acc[0][3] = fmaf(a.x, b.w, acc[0][3]);
            acc[1][0] = fmaf(a.y, b.x, acc[1][0]); acc[1][1] = fmaf(a.y, b.y, acc[1][1]);
            acc[1][2] = fmaf(a.y, b.z, acc[1][2]); acc[1][3] = fmaf(a.y, b.w, acc[1][3]);
            acc[2][0] = fmaf(a.z, b.x, acc[2][0]); acc[2][1] = fmaf(a.z, b.y, acc[2][1]);
            acc[2][2] = fmaf(a.z, b.z, acc[2][2]); acc[2][3] = fmaf(a.z, b.w, acc[2][3]);
            acc[3][0] = fmaf(a.w, b.x, acc[3][0]); acc[3][1] = fmaf(a.w, b.y, acc[3][1]);
            acc[3][2] = fmaf(a.w, b.z, acc[3][2]); acc[3][3] = fmaf(a.w, b.w, acc[3][3]);
        }
        __syncthreads();
    }
    #pragma unroll
    for (int i = 0; i < 4; ++i) {
        float4 o; o.x = acc[i][0]; o.y = acc[i][1]; o.z = acc[i][2]; o.w = acc[i][3];
        *reinterpret_cast<float4*>(&C[(size_t)(bm + (ty << 2) + i) * N + bn + (tx << 2)]) = o;
    }
}

// ---------------------------------------------------------------------------
// RoPE on q, in place. One thread per (s, h, d<64) pair.
// out[d]    = x[d]*cos(f[d])    - x[d+64]*sin(f[d])
// out[d+64] = x[d+64]*cos(f[d+64]) + x[d]*sin(f[d+64])
// ---------------------------------------------------------------------------
__global__ __launch_bounds__(256) void rope_q_kernel(float* __restrict__ q,
                                                     const float* __restrict__ freq)
{
    const int idx = blockIdx.x * 256 + threadIdx.x;   // S_LEN*NHQ*64 total
    const int d = idx & 63;
    const int h = (idx >> 6) & (NHQ - 1);
    const int s = idx >> 11;
    const float f0 = freq[s * HD + d];
    const float f1 = freq[s * HD + d + 64];
    const size_t base = (size_t)s * DQ + h * HD + d;
    const float x0 = q[base], x1 = q[base + 64];
    q[base]      = fmaf(x0, cosf(f0), -x1 * sinf(f0));
    q[base + 64] = fmaf(x1, cosf(f1),  x0 * sinf(f1));
}

// RoPE on k + transpose (s,h,d)->(h,s,d) into d_out slot; v transposed copy.
__global__ __launch_bounds__(256) void rope_kv_kernel(const float* __restrict__ kin,
                                                      const float* __restrict__ vin,
                                                      const float* __restrict__ freq,
                                                      float* __restrict__ kout,
                                                      float* __restrict__ vout)
{
    const int idx = blockIdx.x * 256 + threadIdx.x;   // S_LEN*NHKV*64 total
    const int d = idx & 63;
    const int h = (idx >> 6) & (NHKV - 1);
    const int s = idx >> 9;
    const float f0 = freq[s * HD + d];
    const float f1 = freq[s * HD + d + 64];
    const size_t ib = (size_t)s * DKV + h * HD + d;
    const float x0 = kin[ib], x1 = kin[ib + 64];
    const size_t ob = (size_t)h * S_LEN * HD + (size_t)s * HD + d;
    kout[ob]      = fmaf(x0, cosf(f0), -x1 * sinf(f0));
    kout[ob + 64] = fmaf(x1, cosf(f1),  x0 * sinf(f1));
    vout[ob]      = vin[ib];
    vout[ob + 64] = vin[ib + 64];
}

// ---------------------------------------------------------------------------
// Flash attention fp32. Block = (head h, q-tile of 64 rows), 256 threads.
// K/V read from d_out's k_new/v_new (h,s,d) slots. Online softmax, row stats
// kept redundantly in registers across the owning 16-lane group.
// LDS ~116 KB -> 1 block/CU (baseline; acceptable).
// ---------------------------------------------------------------------------
__global__ __launch_bounds__(256) void flash_attn(const float* __restrict__ Q,
                                                  const float* __restrict__ Kt,
                                                  const float* __restrict__ Vt,
                                                  float* __restrict__ O)
{
    const int h  = blockIdx.x;
    const int qt = blockIdx.y;
    const int hkv = h >> 2;                // GROUPS=4 repeat_interleave
    const int tid = threadIdx.x;
    const int tx = tid & 15, ty = tid >> 4;
    const int ty4 = ty << 2, tx4 = tx << 2;

    __shared__ __align__(16) float Qs[64][HD + 1];  // stride 129: (row+d)%32 banks, <=2-way
    __shared__ __align__(16) float Ks[64][HD + 1];
    __shared__ __align__(16) float Vs[64][HD + 1];
    __shared__ __align__(16) float Ps[64][65];      // stride 65: (row+k)%32 banks

    const float qscale = 0.08838834764831845f;      // 1/sqrt(128), folded into Q

    #pragma unroll
    for (int l = 0; l < 8; ++l) {
        const int idx = tid + l * 256;
        const int r  = idx >> 5;
        const int d4 = (idx & 31) << 2;
        const float4 v = *reinterpret_cast<const float4*>(&Q[(size_t)(qt * 64 + r) * DQ + h * HD + d4]);
        Qs[r][d4 + 0] = v.x * qscale; Qs[r][d4 + 1] = v.y * qscale;
        Qs[r][d4 + 2] = v.z * qscale; Qs[r][d4 + 3] = v.w * qscale;
    }

    float accO[4][8];
    #pragma unroll
    for (int i = 0; i < 4; ++i)
        #pragma unroll
        for (int j = 0; j < 8; ++j) accO[i][j] = 0.f;
    float m_i[4] = {-1e30f, -1e30f, -1e30f, -1e30f};
    float l_i[4] = {0.f, 0.f, 0.f, 0.f};

    const size_t kvbase = (size_t)hkv * S_LEN * HD;

    for (int kt = 0; kt <= qt; ++kt) {
        __syncthreads();    // guards Qs on iter 0, Ks/Vs reuse afterwards
        #pragma unroll
        for (int l = 0; l < 8; ++l) {
            const int idx = tid + l * 256;
            const int r  = idx >> 5;
            const int d4 = (idx & 31) << 2;
            const float4 kv = *reinterpret_cast<const float4*>(&Kt[kvbase + (size_t)(kt * 64 + r) * HD + d4]);
            Ks[r][d4 + 0] = kv.x; Ks[r][d4 + 1] = kv.y; Ks[r][d4 + 2] = kv.z; Ks[r][d4 + 3] = kv.w;
            const float4 vv = *reinterpret_cast<const float4*>(&Vt[kvbase + (size_t)(kt * 64 + r) * HD + d4]);
            Vs[r][d4 + 0] = vv.x; Vs[r][d4 + 1] = vv.y; Vs[r][d4 + 2] = vv.z; Vs[r][d4 + 3] = vv.w;
        }
        __syncthreads();

        // Scores: s4[i][j] = (Q*scale) . K  for rows ty4+i, cols tx4+j
        float s4[4][4] = {};
        #pragma unroll 4
        for (int d = 0; d < HD; ++d) {
            const float a0 = Qs[ty4 + 0][d], a1 = Qs[ty4 + 1][d];
            const float a2 = Qs[ty4 + 2][d], a3 = Qs[ty4 + 3][d];
            const float b0 = Ks[tx4 + 0][d], b1 = Ks[tx4 + 1][d];
            const float b2 = Ks[tx4 + 2][d], b3 = Ks[tx4 + 3][d];
            s4[0][0] = fmaf(a0, b0, s4[0][0]); s4[0][1] = fmaf(a0, b1, s4[0][1]);
            s4[0][2] = fmaf(a0, b2, s4[0][2]); s4[0][3] = fmaf(a0, b3, s4[0][3]);
            s4[1][0] = fmaf(a1, b0, s4[1][0]); s4[1][1] = fmaf(a1, b1, s4[1][1]);
            s4[1][2] = fmaf(a1, b2, s4[1][2]); s4[1][3] = fmaf(a1, b3, s4[1][3]);
            s4[2][0] = fmaf(a2, b0, s4[2][0]); s4[2][1] = fmaf(a2, b1, s4[2][1]);
            s4[2][2] = fmaf(a2, b2, s4[2][2]); s4[2][3] = fmaf(a2, b3, s4[2][3]);
            s4[3][0] = fmaf(a3, b0, s4[3][0]); s4[3][1] = fmaf(a3, b1, s4[3][1]);
            s4[3][2] = fmaf(a3, b2, s4[3][2]); s4[3][3] = fmaf(a3, b3, s4[3][3]);
        }

        if (kt == qt) {       // causal mask within diagonal tile
            #pragma unroll
            for (int i = 0; i < 4; ++i)
                #pragma unroll
                for (int j = 0; j < 4; ++j)
                    if (tx4 + j > ty4 + i) s4[i][j] = -1e30f;
        }

        // Online softmax per row; all 16 lanes of a row-group compute the
        // same stats redundantly (shfl_xor within the 16-lane group).
        #pragma unroll
        for (int i = 0; i < 4; ++i) {
            float rmax = fmaxf(fmaxf(s4[i][0], s4[i][1]), fmaxf(s4[i][2], s4[i][3]));
            rmax = fmaxf(rmax, __shfl_xor(rmax, 1));
            rmax = fmaxf(rmax, __shfl_xor(rmax, 2));
            rmax = fmaxf(rmax, __shfl_xor(rmax, 4));
            rmax = fmaxf(rmax, __shfl_xor(rmax, 8));
            const float mnew = fmaxf(m_i[i], rmax);
            const float csc = __expf(m_i[i] - mnew);
            const float p0 = __expf(s4[i][0] - mnew);
            const float p1 = __expf(s4[i][1] - mnew);
            const float p2 = __expf(s4[i][2] - mnew);
            const float p3 = __expf(s4[i][3] - mnew);
            Ps[ty4 + i][tx4 + 0] = p0; Ps[ty4 + i][tx4 + 1] = p1;
            Ps[ty4 + i][tx4 + 2] = p2; Ps[ty4 + i][tx4 + 3] = p3;
            float rsum = p0 + p1 + p2 + p3;
            rsum += __shfl_xor(rsum, 1);
            rsum += __shfl_xor(rsum, 2);
            rsum += __shfl_xor(rsum, 4);
            rsum += __shfl_xor(rsum, 8);
            l_i[i] = l_i[i] * csc + rsum;
            m_i[i] = mnew;
            #pragma unroll
            for (int j = 0; j < 8; ++j) accO[i][j] *= csc;
        }
        __syncthreads();

        // PV: accO[i][j] += P[row][k] * V[k][tx+16j]
        #pragma unroll 2
        for (int k = 0; k < 64; ++k) {
            const float p0 = Ps[ty4 + 0][k], p1 = Ps[ty4 + 1][k];
            const float p2 = Ps[ty4 + 2][k], p3 = Ps[ty4 + 3][k];
            #pragma unroll
            for (int j = 0; j < 8; ++j) {
                const float vv = Vs[k][tx + (j << 4)];
                accO[0][j] = fmaf(p0, vv, accO[0][j]);
                accO[1][j] = fmaf(p1, vv, accO[1][j]);
                accO[2][j] = fmaf(p2, vv, accO[2][j]);
                accO[3][j] = fmaf(p3, vv, accO[3][j]);
            }
        }
    }

    #pragma unroll
    for (int i = 0; i < 4; ++i) {
        const float inv = 1.f / l_i[i];
        #pragma unroll
        for (int j = 0; j < 8; ++j) {
            O[(size_t)(qt * 64 + ty4 + i) * DQ + h * HD + tx + (j << 4)] = accO[i][j] * inv;
        }
    }
}

// ---------------------------------------------------------------------------
// d_out layout (fp32): [ out: S*DQ | k_new: NHKV*S*HD | v_new: NHKV*S*HD ]
// d_ws  layout (fp32): [ q: S*DQ | k_tmp: S*DKV | v_tmp: S*DKV | attn: S*DQ ]
//                       = 20,971,520 floats = 80 MiB
// ---------------------------------------------------------------------------
extern "C" void kernel_launch(void* const* d_in, const int* in_sizes, int n_in,
                              void* d_out, int out_size, void* d_ws, size_t ws_size,
                              hipStream_t stream)
{
    const float* x    = (const float*)d_in[0];
    const float* freq = (const float*)d_in[1];
    const float* wq   = (const float*)d_in[2];
    const float* wk   = (const float*)d_in[3];
    const float* wv   = (const float*)d_in[4];
    const float* wo   = (const float*)d_in[5];

    float* out  = (float*)d_out;
    float* kout = out + (size_t)S_LEN * DQ;
    float* vout = kout + (size_t)NHKV * S_LEN * HD;

    float* ws   = (float*)d_ws;
    float* q    = ws;
    float* ktmp = q + (size_t)S_LEN * DQ;
    float* vtmp = ktmp + (size_t)S_LEN * DKV;
    float* attn = vtmp + (size_t)S_LEN * DKV;

    const dim3 blk(256);

    // Projections: q = x@wq^T, k = x@wk^T, v = x@wv^T
    gemm_abt<<<dim3(DQ / TN, S_LEN / TM), blk, 0, stream>>>(x, wq, q, S_LEN, DQ, DMODEL);
    gemm_abt<<<dim3(DKV / TN, S_LEN / TM), blk, 0, stream>>>(x, wk, ktmp, S_LEN, DKV, DMODEL);
    gemm_abt<<<dim3(DKV / TN, S_LEN / TM), blk, 0, stream>>>(x, wv, vtmp, S_LEN, DKV, DMODEL);

    // RoPE (+ transpose k/v straight into their d_out slots)
    rope_q_kernel<<<S_LEN * NHQ * 64 / 256, blk, 0, stream>>>(q, freq);
    rope_kv_kernel<<<S_LEN * NHKV * 64 / 256, blk, 0, stream>>>(ktmp, vtmp, freq, kout, vout);

    // Attention (reads k_new/v_new from d_out)
    flash_attn<<<dim3(NHQ, S_LEN / 64), blk, 0, stream>>>(q, kout, vout, attn);

    // Output projection
    gemm_abt<<<dim3(DMODEL / TN, S_LEN / TM), blk, 0, stream>>>(attn, wo, out, S_LEN, DMODEL, DMODEL);
}

// Round 2
// 663.048 us; speedup vs baseline: 5.5235x; 5.5235x over previous
//
#include <hip/hip_runtime.h>
#include <math.h>

#define S_LEN 2048
#define DMODEL 4096
#define NHQ 32
#define NHKV 8
#define HD 128
#define DQ 4096
#define DKV 1024

typedef __attribute__((ext_vector_type(8))) short bf16x8;
typedef __attribute__((ext_vector_type(4))) float f32x4;
typedef __attribute__((ext_vector_type(8))) unsigned short u16x8;

__device__ __forceinline__ unsigned short f2bf(float f) {
    unsigned u = __builtin_bit_cast(unsigned, f);
    u += 0x7fffu + ((u >> 16) & 1u);     // round-to-nearest-even
    return (unsigned short)(u >> 16);
}

__device__ __forceinline__ void gload16(const void* g, void* l) {
    __builtin_amdgcn_global_load_lds(
        (const __attribute__((address_space(1))) unsigned int*)g,
        (__attribute__((address_space(3))) unsigned int*)l, 16, 0, 0);
}

// ---------------------------------------------------------------------------
// fp32 -> bf16 bulk convert (8 elems/thread/iter)
// ---------------------------------------------------------------------------
__global__ __launch_bounds__(256) void cvt_bf16(const float* __restrict__ src,
                                                unsigned short* __restrict__ dst, int n8)
{
    for (int i = blockIdx.x * 256 + threadIdx.x; i < n8; i += gridDim.x * 256) {
        const float4 a = ((const float4*)src)[2 * i];
        const float4 b = ((const float4*)src)[2 * i + 1];
        u16x8 o;
        o[0] = f2bf(a.x); o[1] = f2bf(a.y); o[2] = f2bf(a.z); o[3] = f2bf(a.w);
        o[4] = f2bf(b.x); o[5] = f2bf(b.y); o[6] = f2bf(b.z); o[7] = f2bf(b.w);
        ((u16x8*)dst)[i] = o;
    }
}

// ---------------------------------------------------------------------------
// bf16 MFMA GEMM (m97 structure): C[M,N] = A[M,K] * B[N,K]^T, fp32 out.
// 128x128 tile, BK=32, 4 waves (2x2), 4x4 fragments/wave, 16x16x32 MFMA.
// Linear LDS + global_load_lds width 16, 2-barrier loop.
// ---------------------------------------------------------------------------
#define BBM 128
#define BBN 128
#define BBK 32

__global__ __launch_bounds__(256) void gemm_bf16(const unsigned short* __restrict__ A,
                                                 const unsigned short* __restrict__ B,
                                                 float* __restrict__ C,
                                                 int M, int N, int K)
{
    __shared__ __align__(16) unsigned short As[BBM * BBK];  // [128][32] linear
    __shared__ __align__(16) unsigned short Bs[BBN * BBK];

    const int tid  = threadIdx.x;
    const int lane = tid & 63;
    const int w    = tid >> 6;
    const int wy   = w >> 1, wx = w & 1;
    const int bm = blockIdx.y * BBM, bn = blockIdx.x * BBN;
    const int l15 = lane & 15;
    const int lk16 = (lane >> 4) * 16;            // byte offset of k-slice
    const int ldsWaveBase = (tid & 192) * 16;

    f32x4 acc[4][4];
    #pragma unroll
    for (int m = 0; m < 4; ++m)
        #pragma unroll
        for (int n = 0; n < 4; ++n) acc[m][n] = (f32x4){0.f, 0.f, 0.f, 0.f};

    const char* Ab = (const char*)A;
    const char* Bb = (const char*)B;
    char* AsB = (char*)As;
    char* BsB = (char*)Bs;

    for (int k0 = 0; k0 < K; k0 += BBK) {
        __syncthreads();                          // prev compute done before overwrite
        #pragma unroll
        for (int c = 0; c < 2; ++c) {
            const int i = tid + c * 256;          // chunk 0..511
            const int r = i >> 2;                 // tile row 0..127
            const int co = (i & 3) << 4;          // byte in row (64B rows)
            gload16(Ab + ((size_t)(bm + r) * K + k0) * 2 + co, AsB + ldsWaveBase + c * 4096);
            gload16(Bb + ((size_t)(bn + r) * K + k0) * 2 + co, BsB + ldsWaveBase + c * 4096);
        }
        __syncthreads();                          // compiler drains vmcnt before barrier

        bf16x8 af[4], bfr[4];
        #pragma unroll
        for (int m = 0; m < 4; ++m)
            af[m] = *(const bf16x8*)(AsB + (wy * 64 + m * 16 + l15) * 64 + lk16);
        #pragma unroll
        for (int n = 0; n < 4; ++n)
            bfr[n] = *(const bf16x8*)(BsB + (wx * 64 + n * 16 + l15) * 64 + lk16);
        #pragma unroll
        for (int m = 0; m < 4; ++m)
            #pragma unroll
            for (int n = 0; n < 4; ++n)
                acc[m][n] = __builtin_amdgcn_mfma_f32_16x16x32_bf16(af[m], bfr[n], acc[m][n], 0, 0, 0);
    }

    // C/D layout: col = lane&15, row = (lane>>4)*4 + reg  [m89 verified]
    const int rg = (lane >> 4) * 4;
    #pragma unroll
    for (int m = 0; m < 4; ++m)
        #pragma unroll
        for (int n = 0; n < 4; ++n) {
            float* Cp = C + (size_t)(bm + wy * 64 + m * 16 + rg) * N + bn + wx * 64 + n * 16 + l15;
            #pragma unroll
            for (int r = 0; r < 4; ++r) Cp[(size_t)r * N] = acc[m][n][r];
        }
}

// ---------------------------------------------------------------------------
// RoPE on q (fp32 in) -> q_bf [h][s][d] bf16
// ---------------------------------------------------------------------------
__global__ __launch_bounds__(256) void rope_q(const float* __restrict__ q,
                                              const float* __restrict__ freq,
                                              unsigned short* __restrict__ qbf)
{
    const int idx = blockIdx.x * 256 + threadIdx.x;  // NHQ*S*64
    const int d = idx & 63;
    const int s = (idx >> 6) & (S_LEN - 1);
    const int h = idx >> 17;
    const float f0 = freq[s * HD + d];
    const float f1 = freq[s * HD + d + 64];
    const float x0 = q[(size_t)s * DQ + h * HD + d];
    const float x1 = q[(size_t)s * DQ + h * HD + d + 64];
    const size_t ob = ((size_t)h * S_LEN + s) * HD + d;
    qbf[ob]      = f2bf(x0 * cosf(f0) - x1 * sinf(f0));
    qbf[ob + 64] = f2bf(x1 * cosf(f1) + x0 * sinf(f1));
}

// ---------------------------------------------------------------------------
// RoPE on k + transpose into d_out (fp32) and k_bf [h][s][d]; v copied to d_out.
// kv: fused [s][2048] (cols 0..1023 = k, 1024..2047 = v)
// ---------------------------------------------------------------------------
__global__ __launch_bounds__(256) void rope_kv(const float* __restrict__ kv,
                                               const float* __restrict__ freq,
                                               float* __restrict__ knew,
                                               float* __restrict__ vnew,
                                               unsigned short* __restrict__ kbf)
{
    const int idx = blockIdx.x * 256 + threadIdx.x;  // NHKV*S*64
    const int d = idx & 63;
    const int s = (idx >> 6) & (S_LEN - 1);
    const int h = idx >> 17;
    const float f0 = freq[s * HD + d];
    const float f1 = freq[s * HD + d + 64];
    const size_t ib = (size_t)s * 2048 + h * HD + d;
    const float k0 = kv[ib], k1 = kv[ib + 64];
    const float v0 = kv[ib + 1024], v1 = kv[ib + 1024 + 64];
    const float k0r = k0 * cosf(f0) - k1 * sinf(f0);
    const float k1r = k1 * cosf(f1) + k0 * sinf(f1);
    const size_t ob = ((size_t)h * S_LEN + s) * HD + d;
    knew[ob] = k0r;       knew[ob + 64] = k1r;
    vnew[ob] = v0;        vnew[ob + 64] = v1;
    kbf[ob]  = f2bf(k0r); kbf[ob + 64]  = f2bf(k1r);
}

// ---------------------------------------------------------------------------
// V transpose: kvtmp fp32 v-part [s][d] -> vT bf16 [h][d][s]  (LDS-tiled)
// ---------------------------------------------------------------------------
__global__ __launch_bounds__(256) void transp_v(const float* __restrict__ kv,
                                                unsigned short* __restrict__ vT)
{
    __shared__ unsigned short T[64][72];
    const int s0 = blockIdx.x * 64;
    const int dt = blockIdx.y & 1;
    const int h  = blockIdx.y >> 1;
    const int d0 = dt * 64;
    const int tid = threadIdx.x;
    #pragma unroll
    for (int c = 0; c < 4; ++c) {
        const int i = tid + c * 256;              // 0..1023
        const int r  = i >> 4;                    // s row 0..63
        const int cc = (i & 15) * 4;              // d col
        const float4 v = *(const float4*)(kv + (size_t)(s0 + r) * 2048 + 1024 + h * HD + d0 + cc);
        T[r][cc + 0] = f2bf(v.x); T[r][cc + 1] = f2bf(v.y);
        T[r][cc + 2] = f2bf(v.z); T[r][cc + 3] = f2bf(v.w);
    }
    __syncthreads();
    #pragma unroll
    for (int c = 0; c < 2; ++c) {
        const int i = tid + c * 256;              // 0..511
        const int dr = i >> 3;                    // 0..63
        const int sc = (i & 7) * 8;
        u16x8 o;
        #pragma unroll
        for (int j = 0; j < 8; ++j) o[j] = T[sc + j][dr];
        *(u16x8*)(vT + ((size_t)(h * HD + d0 + dr)) * S_LEN + s0 + sc) = o;
    }
}

// ---------------------------------------------------------------------------
// MFMA flash attention. Block = (head, 64 q-rows), 4 waves x 16 q-rows.
// K/Q LDS [64][128] bf16, V LDS [128][64] (pre-transposed global), all
// XOR-swizzled: stored LDS[row*RB + (byte ^ ((row&7)<<4))], achieved via
// pre-swizzled global source chunks (global_load_lds writes linearly).
// ---------------------------------------------------------------------------
__global__ __launch_bounds__(256) void flash_bf16(const unsigned short* __restrict__ Qbf,  // [h][s][d]
                                                  const unsigned short* __restrict__ Kbf,  // [hkv][s][d]
                                                  const unsigned short* __restrict__ VbfT, // [hkv][d][s]
                                                  unsigned short* __restrict__ Obf)        // [s][4096]
{
    __shared__ __align__(16) unsigned short Qs[64 * 128];
    __shared__ __align__(16) unsigned short Ks[64 * 128];
    __shared__ __align__(16) unsigned short Vs[128 * 64];
    __shared__ __align__(16) unsigned short Ps[4][16 * 64];

    const int h  = blockIdx.x;
    const int qt = blockIdx.y;
    const int hkv = h >> 2;
    const int tid = threadIdx.x;
    const int lane = tid & 63;
    const int w = tid >> 6;
    const int l15 = lane & 15;
    const int l4  = lane >> 4;
    const int ldsWaveBase = (tid & 192) * 16;

    const char* Qg = (const char*)Qbf + ((size_t)h * S_LEN + (size_t)qt * 64) * HD * 2;
    const char* Kg = (const char*)Kbf + (size_t)hkv * S_LEN * HD * 2;
    const char* Vg = (const char*)VbfT + (size_t)hkv * HD * S_LEN * 2;

    // Stage Q once (1024 chunks, source pre-swizzled by row&7)
    #pragma unroll
    for (int c = 0; c < 4; ++c) {
        const int i = tid + c * 256;
        const int qr = i >> 4;
        const int cc = (i & 15) ^ (qr & 7);
        gload16(Qg + (size_t)qr * 256 + cc * 16, (char*)Qs + ldsWaveBase + c * 4096);
    }

    f32x4 accO[8];
    #pragma unroll
    for (int n = 0; n < 8; ++n) accO[n] = (f32x4){0.f, 0.f, 0.f, 0.f};
    float m_i[4] = {-3e38f, -3e38f, -3e38f, -3e38f};
    float l_i[4] = {0.f, 0.f, 0.f, 0.f};
    const float qscale = 0.08838834764831845f;   // 1/sqrt(128)

    for (int kt = 0; kt <= qt; ++kt) {
        __syncthreads();     // prev iter's reads done (also drains Q loads at kt=0)
        #pragma unroll
        for (int c = 0; c < 4; ++c) {
            const int i = tid + c * 256;
            const int kr = i >> 4;
            const int cc = (i & 15) ^ (kr & 7);
            gload16(Kg + (size_t)(kt * 64 + kr) * 256 + cc * 16, (char*)Ks + ldsWaveBase + c * 4096);
        }
        #pragma unroll
        for (int c = 0; c < 4; ++c) {
            const int i = tid + c * 256;
            const int dr = i >> 3;
            const int cc = (i & 7) ^ (dr & 7);
            gload16(Vg + (size_t)dr * (S_LEN * 2) + (size_t)kt * 128 + cc * 16,
                    (char*)Vs + ldsWaveBase + c * 4096);
        }
        __syncthreads();

        // ---- QK^T: 16 MFMAs/wave ----
        f32x4 sacc[4];
        #pragma unroll
        for (int n = 0; n < 4; ++n) sacc[n] = (f32x4){0.f, 0.f, 0.f, 0.f};
        const int qrow = w * 16;
        #pragma unroll
        for (int kb = 0; kb < 4; ++kb) {
            const int arow = qrow + l15;
            const bf16x8 aq = *(const bf16x8*)((const char*)Qs + arow * 256 +
                                 ((kb * 64 + l4 * 16) ^ ((arow & 7) << 4)));
            #pragma unroll
            for (int n = 0; n < 4; ++n) {
                const int krow = n * 16 + l15;
                const bf16x8 bk = *(const bf16x8*)((const char*)Ks + krow * 256 +
                                     ((kb * 64 + l4 * 16) ^ ((krow & 7) << 4)));
                sacc[n] = __builtin_amdgcn_mfma_f32_16x16x32_bf16(aq, bk, sacc[n], 0, 0, 0);
            }
        }

        // ---- online softmax (wave-parallel, 16-lane groups) ----
        unsigned short* Pw = &Ps[w][0];
        float csc[4];
        #pragma unroll
        for (int reg = 0; reg < 4; ++reg) {
            const int qglob = qt * 64 + qrow + l4 * 4 + reg;
            float s0 = sacc[0][reg] * qscale;
            float s1 = sacc[1][reg] * qscale;
            float s2 = sacc[2][reg] * qscale;
            float s3 = sacc[3][reg] * qscale;
            if (kt == qt) {
                const int kvb = kt * 64 + l15;
                if (kvb +  0 > qglob) s0 = -3e38f;
                if (kvb + 16 > qglob) s1 = -3e38f;
                if (kvb + 32 > qglob) s2 = -3e38f;
                if (kvb + 48 > qglob) s3 = -3e38f;
            }
            float rmax = fmaxf(fmaxf(s0, s1), fmaxf(s2, s3));
            rmax = fmaxf(rmax, __shfl_xor(rmax, 1));
            rmax = fmaxf(rmax, __shfl_xor(rmax, 2));
            rmax = fmaxf(rmax, __shfl_xor(rmax, 4));
            rmax = fmaxf(rmax, __shfl_xor(rmax, 8));
            const float mnew = fmaxf(m_i[reg], rmax);
            csc[reg] = __expf(m_i[reg] - mnew);
            m_i[reg] = mnew;
            const float p0 = __expf(s0 - mnew);
            const float p1 = __expf(s1 - mnew);
            const float p2 = __expf(s2 - mnew);
            const float p3 = __expf(s3 - mnew);
            const int rl = l4 * 4 + reg;
            const int sf = (rl & 7) << 4;
            *(unsigned short*)((char*)Pw + rl * 128 + (( 0 + l15 * 2) ^ sf)) = f2bf(p0);
            *(unsigned short*)((char*)Pw + rl * 128 + ((32 + l15 * 2) ^ sf)) = f2bf(p1);
            *(unsigned short*)((char*)Pw + rl * 128 + ((64 + l15 * 2) ^ sf)) = f2bf(p2);
            *(unsigned short*)((char*)Pw + rl * 128 + ((96 + l15 * 2) ^ sf)) = f2bf(p3);
            float rsum = p0 + p1 + p2 + p3;
            rsum += __shfl_xor(rsum, 1);
            rsum += __shfl_xor(rsum, 2);
            rsum += __shfl_xor(rsum, 4);
            rsum += __shfl_xor(rsum, 8);
            l_i[reg] = l_i[reg] * csc[reg] + rsum;
        }
        #pragma unroll
        for (int n = 0; n < 8; ++n) {
            accO[n][0] *= csc[0]; accO[n][1] *= csc[1];
            accO[n][2] *= csc[2]; accO[n][3] *= csc[3];
        }

        // ---- PV: 16 MFMAs/wave (P from own wave's strip; no barrier needed) ----
        const char* Pwb = (const char*)Pw;
        #pragma unroll
        for (int kb = 0; kb < 2; ++kb) {
            const int prow = l15;
            const bf16x8 pa = *(const bf16x8*)(Pwb + prow * 128 +
                                 ((kb * 64 + l4 * 16) ^ ((prow & 7) << 4)));
            #pragma unroll
            for (int n = 0; n < 8; ++n) {
                const int vrow = n * 16 + l15;
                const bf16x8 vb = *(const bf16x8*)((const char*)Vs + vrow * 128 +
                                     ((kb * 64 + l4 * 16) ^ ((vrow & 7) << 4)));
                accO[n] = __builtin_amdgcn_mfma_f32_16x16x32_bf16(pa, vb, accO[n], 0, 0, 0);
            }
        }
    }

    // ---- epilogue: O / l, write bf16 [s][4096] ----
    float invl[4];
    #pragma unroll
    for (int reg = 0; reg < 4; ++reg) invl[reg] = 1.f / l_i[reg];
    #pragma unroll
    for (int n = 0; n < 8; ++n)
        #pragma unroll
        for (int reg = 0; reg < 4; ++reg) {
            const int row = qt * 64 + w * 16 + l4 * 4 + reg;
            Obf[(size_t)row * DQ + h * HD + n * 16 + l15] = f2bf(accO[n][reg] * invl[reg]);
        }
}

// ---------------------------------------------------------------------------
// d_out (fp32): [ out: S*DQ | k_new: NHKV*S*HD | v_new: NHKV*S*HD ]
// d_ws bytes:
//   x_bf   16MB | wq_bf/wo_bf 32MB | wkv_bf 16MB | q_f32 32MB (attn_bf aliases)
//   kvtmp  16MB | q_bf 16MB | k_bf 4MB | vT_bf 4MB          total 136MB
// ---------------------------------------------------------------------------
extern "C" void kernel_launch(void* const* d_in, const int* in_sizes, int n_in,
                              void* d_out, int out_size, void* d_ws, size_t ws_size,
                              hipStream_t stream)
{
    const float* x    = (const float*)d_in[0];
    const float* freq = (const float*)d_in[1];
    const float* wq   = (const float*)d_in[2];
    const float* wk   = (const float*)d_in[3];
    const float* wv   = (const float*)d_in[4];
    const float* wo   = (const float*)d_in[5];

    float* out  = (float*)d_out;
    float* knew = out + (size_t)S_LEN * DQ;
    float* vnew = knew + (size_t)NHKV * S_LEN * HD;

    char* ws = (char*)d_ws;
    unsigned short* x_bf   = (unsigned short*)(ws);                          // 16 MB
    unsigned short* wq_bf  = (unsigned short*)(ws + (16u << 20));            // 32 MB (reused for wo)
    unsigned short* wkv_bf = (unsigned short*)(ws + (48u << 20));            // 16 MB
    float*          q_f32  = (float*)(ws + (64u << 20));                     // 32 MB
    unsigned short* attn_bf= (unsigned short*)(ws + (64u << 20));            // aliases q_f32 (dead by then)
    float*          kvtmp  = (float*)(ws + (96u << 20));                     // 16 MB
    unsigned short* q_bf   = (unsigned short*)(ws + (112u << 20));           // 16 MB
    unsigned short* k_bf   = (unsigned short*)(ws + (128u << 20));           // 4 MB
    unsigned short* vT_bf  = (unsigned short*)(ws + (132u << 20));           // 4 MB

    const dim3 blk(256);

    // bf16 conversions
    cvt_bf16<<<2048, blk, 0, stream>>>(x,  x_bf,   S_LEN * DMODEL / 8);
    cvt_bf16<<<2048, blk, 0, stream>>>(wq, wq_bf,  DQ * DMODEL / 8);
    cvt_bf16<<<2048, blk, 0, stream>>>(wk, wkv_bf, DKV * DMODEL / 8);
    cvt_bf16<<<2048, blk, 0, stream>>>(wv, wkv_bf + (size_t)DKV * DMODEL, DKV * DMODEL / 8);

    // Q projection: [2048,4096] = x @ wq^T
    gemm_bf16<<<dim3(DQ / BBN, S_LEN / BBM), blk, 0, stream>>>(x_bf, wq_bf, q_f32, S_LEN, DQ, DMODEL);

    // wo conversion into wq_bf's slot (wq dead after Q-proj)
    cvt_bf16<<<2048, blk, 0, stream>>>(wo, wq_bf, DMODEL * DQ / 8);

    // fused K+V projection: [2048,2048] = x @ [wk;wv]^T
    gemm_bf16<<<dim3(2048 / BBN, S_LEN / BBM), blk, 0, stream>>>(x_bf, wkv_bf, kvtmp, S_LEN, 2048, DMODEL);

    // RoPE + layout transforms
    rope_q<<<NHQ * S_LEN * 64 / 256, blk, 0, stream>>>(q_f32, freq, q_bf);
    rope_kv<<<NHKV * S_LEN * 64 / 256, blk, 0, stream>>>(kvtmp, freq, knew, vnew, k_bf);
    transp_v<<<dim3(S_LEN / 64, 2 * NHKV), blk, 0, stream>>>(kvtmp, vT_bf);

    // flash attention -> attn_bf [s][4096]
    flash_bf16<<<dim3(NHQ, S_LEN / 64), blk, 0, stream>>>(q_bf, k_bf, vT_bf, attn_bf);

    // output projection: out = attn @ wo^T
    gemm_bf16<<<dim3(DMODEL / BBN, S_LEN / BBM), blk, 0, stream>>>(attn_bf, wq_bf, out, S_LEN, DMODEL, DMODEL);
}

// Round 3
// 589.417 us; speedup vs baseline: 6.2135x; 1.1249x over previous
//
#include <hip/hip_runtime.h>
#include <math.h>

#define S_LEN 2048
#define DMODEL 4096
#define NHQ 32
#define NHKV 8
#define HD 128
#define DQ 4096
#define DKV 1024
#define NQKV 6144   // 4096 q + 1024 k + 1024 v

typedef __attribute__((ext_vector_type(8))) short bf16x8;
typedef __attribute__((ext_vector_type(4))) float f32x4;
typedef __attribute__((ext_vector_type(8))) unsigned short u16x8;

__device__ __forceinline__ unsigned short f2bf(float f) {
    unsigned u = __builtin_bit_cast(unsigned, f);
    u += 0x7fffu + ((u >> 16) & 1u);     // round-to-nearest-even
    return (unsigned short)(u >> 16);
}

__device__ __forceinline__ void gload16(const void* g, void* l) {
    __builtin_amdgcn_global_load_lds(
        (const __attribute__((address_space(1))) unsigned int*)g,
        (__attribute__((address_space(3))) unsigned int*)l, 16, 0, 0);
}

// ---------------------------------------------------------------------------
// fp32 -> bf16 bulk convert (8 elems/thread/iter)
// ---------------------------------------------------------------------------
__global__ __launch_bounds__(256) void cvt_bf16(const float* __restrict__ src,
                                                unsigned short* __restrict__ dst, int n8)
{
    for (int i = blockIdx.x * 256 + threadIdx.x; i < n8; i += gridDim.x * 256) {
        const float4 a = ((const float4*)src)[2 * i];
        const float4 b = ((const float4*)src)[2 * i + 1];
        u16x8 o;
        o[0] = f2bf(a.x); o[1] = f2bf(a.y); o[2] = f2bf(a.z); o[3] = f2bf(a.w);
        o[4] = f2bf(b.x); o[5] = f2bf(b.y); o[6] = f2bf(b.z); o[7] = f2bf(b.w);
        ((u16x8*)dst)[i] = o;
    }
}

// ---------------------------------------------------------------------------
// bf16 MFMA GEMM (m97 structure): C[M,N] = A[M,K] * B[N,K]^T, fp32 out.
// 128x128 tile, BK=32, 4 waves (2x2), 4x4 fragments/wave, 16x16x32 MFMA.
// ---------------------------------------------------------------------------
#define BBM 128
#define BBN 128
#define BBK 32

__global__ __launch_bounds__(256) void gemm_bf16(const unsigned short* __restrict__ A,
                                                 const unsigned short* __restrict__ B,
                                                 float* __restrict__ C,
                                                 int M, int N, int K)
{
    __shared__ __align__(16) unsigned short As[BBM * BBK];
    __shared__ __align__(16) unsigned short Bs[BBN * BBK];

    const int tid  = threadIdx.x;
    const int lane = tid & 63;
    const int w    = tid >> 6;
    const int wy   = w >> 1, wx = w & 1;
    const int bm = blockIdx.y * BBM, bn = blockIdx.x * BBN;
    const int l15 = lane & 15;
    const int lk16 = (lane >> 4) * 16;
    const int ldsWaveBase = (tid & 192) * 16;

    f32x4 acc[4][4];
    #pragma unroll
    for (int m = 0; m < 4; ++m)
        #pragma unroll
        for (int n = 0; n < 4; ++n) acc[m][n] = (f32x4){0.f, 0.f, 0.f, 0.f};

    const char* Ab = (const char*)A;
    const char* Bb = (const char*)B;
    char* AsB = (char*)As;
    char* BsB = (char*)Bs;

    for (int k0 = 0; k0 < K; k0 += BBK) {
        __syncthreads();
        #pragma unroll
        for (int c = 0; c < 2; ++c) {
            const int i = tid + c * 256;
            const int r = i >> 2;
            const int co = (i & 3) << 4;
            gload16(Ab + ((size_t)(bm + r) * K + k0) * 2 + co, AsB + ldsWaveBase + c * 4096);
            gload16(Bb + ((size_t)(bn + r) * K + k0) * 2 + co, BsB + ldsWaveBase + c * 4096);
        }
        __syncthreads();

        bf16x8 af[4], bfr[4];
        #pragma unroll
        for (int m = 0; m < 4; ++m)
            af[m] = *(const bf16x8*)(AsB + (wy * 64 + m * 16 + l15) * 64 + lk16);
        #pragma unroll
        for (int n = 0; n < 4; ++n)
            bfr[n] = *(const bf16x8*)(BsB + (wx * 64 + n * 16 + l15) * 64 + lk16);
        #pragma unroll
        for (int m = 0; m < 4; ++m)
            #pragma unroll
            for (int n = 0; n < 4; ++n)
                acc[m][n] = __builtin_amdgcn_mfma_f32_16x16x32_bf16(af[m], bfr[n], acc[m][n], 0, 0, 0);
    }

    const int rg = (lane >> 4) * 4;
    #pragma unroll
    for (int m = 0; m < 4; ++m)
        #pragma unroll
        for (int n = 0; n < 4; ++n) {
            float* Cp = C + (size_t)(bm + wy * 64 + m * 16 + rg) * N + bn + wx * 64 + n * 16 + l15;
            #pragma unroll
            for (int r = 0; r < 4; ++r) Cp[(size_t)r * N] = acc[m][n][r];
        }
}

// ---------------------------------------------------------------------------
// RoPE on q (from fused qkv fp32) -> q_bf [h][s][d], pre-scaled by
// qscale * log2(e) so flash can use exp2 directly.
// ---------------------------------------------------------------------------
#define QSC (0.08838834764831845f * 1.4426950408889634f)

__global__ __launch_bounds__(256) void rope_q(const float* __restrict__ qkv,
                                              const float* __restrict__ freq,
                                              unsigned short* __restrict__ qbf)
{
    const int idx = blockIdx.x * 256 + threadIdx.x;  // NHQ*S*64
    const int d = idx & 63;
    const int s = (idx >> 6) & (S_LEN - 1);
    const int h = idx >> 17;
    const float f0 = freq[s * HD + d];
    const float f1 = freq[s * HD + d + 64];
    const float x0 = qkv[(size_t)s * NQKV + h * HD + d];
    const float x1 = qkv[(size_t)s * NQKV + h * HD + d + 64];
    const size_t ob = ((size_t)h * S_LEN + s) * HD + d;
    qbf[ob]      = f2bf((x0 * cosf(f0) - x1 * sinf(f0)) * QSC);
    qbf[ob + 64] = f2bf((x1 * cosf(f1) + x0 * sinf(f1)) * QSC);
}

// ---------------------------------------------------------------------------
// RoPE on k + transpose into d_out (fp32) and k_bf [h][s][d]; v copied.
// qkv: [s][6144], k at cols 4096.., v at cols 5120..
// ---------------------------------------------------------------------------
__global__ __launch_bounds__(256) void rope_kv(const float* __restrict__ qkv,
                                               const float* __restrict__ freq,
                                               float* __restrict__ knew,
                                               float* __restrict__ vnew,
                                               unsigned short* __restrict__ kbf)
{
    const int idx = blockIdx.x * 256 + threadIdx.x;  // NHKV*S*64
    const int d = idx & 63;
    const int s = (idx >> 6) & (S_LEN - 1);
    const int h = idx >> 17;
    const float f0 = freq[s * HD + d];
    const float f1 = freq[s * HD + d + 64];
    const size_t ib = (size_t)s * NQKV + 4096 + h * HD + d;
    const float k0 = qkv[ib], k1 = qkv[ib + 64];
    const float v0 = qkv[ib + 1024], v1 = qkv[ib + 1024 + 64];
    const float k0r = k0 * cosf(f0) - k1 * sinf(f0);
    const float k1r = k1 * cosf(f1) + k0 * sinf(f1);
    const size_t ob = ((size_t)h * S_LEN + s) * HD + d;
    knew[ob] = k0r;       knew[ob + 64] = k1r;
    vnew[ob] = v0;        vnew[ob + 64] = v1;
    kbf[ob]  = f2bf(k0r); kbf[ob + 64]  = f2bf(k1r);
}

// ---------------------------------------------------------------------------
// V transpose: qkv fp32 v-part [s][d] -> vT bf16 [h][d][s]  (LDS-tiled)
// ---------------------------------------------------------------------------
__global__ __launch_bounds__(256) void transp_v(const float* __restrict__ qkv,
                                                unsigned short* __restrict__ vT)
{
    __shared__ unsigned short T[64][72];
    const int s0 = blockIdx.x * 64;
    const int dt = blockIdx.y & 1;
    const int h  = blockIdx.y >> 1;
    const int d0 = dt * 64;
    const int tid = threadIdx.x;
    #pragma unroll
    for (int c = 0; c < 4; ++c) {
        const int i = tid + c * 256;
        const int r  = i >> 4;
        const int cc = (i & 15) * 4;
        const float4 v = *(const float4*)(qkv + (size_t)(s0 + r) * NQKV + 5120 + h * HD + d0 + cc);
        T[r][cc + 0] = f2bf(v.x); T[r][cc + 1] = f2bf(v.y);
        T[r][cc + 2] = f2bf(v.z); T[r][cc + 3] = f2bf(v.w);
    }
    __syncthreads();
    #pragma unroll
    for (int c = 0; c < 2; ++c) {
        const int i = tid + c * 256;
        const int dr = i >> 3;
        const int sc = (i & 7) * 8;
        u16x8 o;
        #pragma unroll
        for (int j = 0; j < 8; ++j) o[j] = T[sc + j][dr];
        *(u16x8*)(vT + ((size_t)(h * HD + d0 + dr)) * S_LEN + s0 + sc) = o;
    }
}

// ---------------------------------------------------------------------------
// MFMA flash attention v2.
//  - Q in registers (16 VGPR/lane), loaded once; pre-scaled log2-domain.
//  - K/V double-buffered, 2-phase pipeline: stage(t+1) issued before
//    compute(t); ONE barrier per tile (drain at loop end).
//  - exp2 softmax + defer-max (THR=8) + setprio around MFMA clusters.
//  - causal load-balance: qt pairing (y even -> y/2, odd -> 31-y/2).
// LDS: K 2x16KB + V 2x16KB + P 8KB = 72KB -> 2 blocks/CU.
// ---------------------------------------------------------------------------
__global__ __launch_bounds__(256) void flash_bf16(const unsigned short* __restrict__ Qbf,  // [h][s][d] scaled
                                                  const unsigned short* __restrict__ Kbf,  // [hkv][s][d]
                                                  const unsigned short* __restrict__ VbfT, // [hkv][d][s]
                                                  unsigned short* __restrict__ Obf)        // [s][4096]
{
    __shared__ __align__(16) unsigned short Ks[2][64 * 128];
    __shared__ __align__(16) unsigned short Vs[2][128 * 64];
    __shared__ __align__(16) unsigned short Ps[4][16 * 64];

    const int h  = blockIdx.x;
    const int yq = blockIdx.y;
    const int qt = (yq & 1) ? (31 - (yq >> 1)) : (yq >> 1);
    const int hkv = h >> 2;
    const int tid = threadIdx.x;
    const int lane = tid & 63;
    const int w = tid >> 6;
    const int l15 = lane & 15;
    const int l4  = lane >> 4;
    const int ldsWaveBase = (tid & 192) * 16;

    const char* Kg = (const char*)Kbf + (size_t)hkv * S_LEN * HD * 2;
    const char* Vg = (const char*)VbfT + (size_t)hkv * HD * S_LEN * 2;

    // Q fragments in registers (row = wave's 16-row strip + l15, k-slice l4)
    bf16x8 qf[4];
    {
        const char* Qg = (const char*)Qbf + ((size_t)h * S_LEN + qt * 64 + w * 16 + l15) * 256;
        #pragma unroll
        for (int kb = 0; kb < 4; ++kb)
            qf[kb] = *(const bf16x8*)(Qg + kb * 64 + l4 * 16);
    }

    // staging: source pre-swizzled by row&7 so swizzled ds_reads see linear data
    auto STAGE = [&](int buf, int kt) {
        #pragma unroll
        for (int c = 0; c < 4; ++c) {
            const int i = tid + c * 256;
            const int kr = i >> 4;
            const int cc = (i & 15) ^ (kr & 7);
            gload16(Kg + (size_t)(kt * 64 + kr) * 256 + cc * 16,
                    (char*)Ks[buf] + ldsWaveBase + c * 4096);
        }
        #pragma unroll
        for (int c = 0; c < 4; ++c) {
            const int i = tid + c * 256;
            const int dr = i >> 3;
            const int cc = (i & 7) ^ (dr & 7);
            gload16(Vg + (size_t)dr * (S_LEN * 2) + (size_t)kt * 128 + cc * 16,
                    (char*)Vs[buf] + ldsWaveBase + c * 4096);
        }
    };

    f32x4 accO[8];
    #pragma unroll
    for (int n = 0; n < 8; ++n) accO[n] = (f32x4){0.f, 0.f, 0.f, 0.f};
    float m_i[4] = {-3e38f, -3e38f, -3e38f, -3e38f};
    float l_i[4] = {0.f, 0.f, 0.f, 0.f};

    STAGE(0, 0);
    __syncthreads();

    for (int kt = 0; kt <= qt; ++kt) {
        const int cbuf = kt & 1;
        if (kt < qt) STAGE(cbuf ^ 1, kt + 1);    // loads in flight during compute

        // ---- QK^T: 16 MFMAs/wave (Q from regs) ----
        f32x4 sacc[4];
        #pragma unroll
        for (int n = 0; n < 4; ++n) sacc[n] = (f32x4){0.f, 0.f, 0.f, 0.f};
        __builtin_amdgcn_s_setprio(1);
        #pragma unroll
        for (int kb = 0; kb < 4; ++kb) {
            #pragma unroll
            for (int n = 0; n < 4; ++n) {
                const int krow = n * 16 + l15;
                const bf16x8 bk = *(const bf16x8*)((const char*)Ks[cbuf] + krow * 256 +
                                     ((kb * 64 + l4 * 16) ^ ((krow & 7) << 4)));
                sacc[n] = __builtin_amdgcn_mfma_f32_16x16x32_bf16(qf[kb], bk, sacc[n], 0, 0, 0);
            }
        }
        __builtin_amdgcn_s_setprio(0);

        // ---- online softmax (log2 domain) ----
        float s0v[4], s1v[4], s2v[4], s3v[4], pm[4];
        #pragma unroll
        for (int reg = 0; reg < 4; ++reg) {
            float s0 = sacc[0][reg], s1 = sacc[1][reg];
            float s2 = sacc[2][reg], s3 = sacc[3][reg];
            if (kt == qt) {
                const int qglob = qt * 64 + w * 16 + l4 * 4 + reg;
                const int kvb = kt * 64 + l15;
                if (kvb +  0 > qglob) s0 = -3e38f;
                if (kvb + 16 > qglob) s1 = -3e38f;
                if (kvb + 32 > qglob) s2 = -3e38f;
                if (kvb + 48 > qglob) s3 = -3e38f;
            }
            float rmax = fmaxf(fmaxf(s0, s1), fmaxf(s2, s3));
            rmax = fmaxf(rmax, __shfl_xor(rmax, 1));
            rmax = fmaxf(rmax, __shfl_xor(rmax, 2));
            rmax = fmaxf(rmax, __shfl_xor(rmax, 4));
            rmax = fmaxf(rmax, __shfl_xor(rmax, 8));
            pm[reg] = rmax;
            s0v[reg] = s0; s1v[reg] = s1; s2v[reg] = s2; s3v[reg] = s3;
        }

        // defer-max: rescale only when the running max grew by > 8 (log2)
        const bool grew = (pm[0] > m_i[0] + 8.f) || (pm[1] > m_i[1] + 8.f) ||
                          (pm[2] > m_i[2] + 8.f) || (pm[3] > m_i[3] + 8.f);
        if (__any(grew)) {
            #pragma unroll
            for (int reg = 0; reg < 4; ++reg) {
                const float mnew = fmaxf(m_i[reg], pm[reg]);
                const float csc = exp2f(m_i[reg] - mnew);
                l_i[reg] *= csc;
                m_i[reg] = mnew;
                #pragma unroll
                for (int n = 0; n < 8; ++n) accO[n][reg] *= csc;
            }
        }

        unsigned short* Pw = &Ps[w][0];
        #pragma unroll
        for (int reg = 0; reg < 4; ++reg) {
            const float p0 = exp2f(s0v[reg] - m_i[reg]);
            const float p1 = exp2f(s1v[reg] - m_i[reg]);
            const float p2 = exp2f(s2v[reg] - m_i[reg]);
            const float p3 = exp2f(s3v[reg] - m_i[reg]);
            const int rl = l4 * 4 + reg;
            const int sf = (rl & 7) << 4;
            *(unsigned short*)((char*)Pw + rl * 128 + (( 0 + l15 * 2) ^ sf)) = f2bf(p0);
            *(unsigned short*)((char*)Pw + rl * 128 + ((32 + l15 * 2) ^ sf)) = f2bf(p1);
            *(unsigned short*)((char*)Pw + rl * 128 + ((64 + l15 * 2) ^ sf)) = f2bf(p2);
            *(unsigned short*)((char*)Pw + rl * 128 + ((96 + l15 * 2) ^ sf)) = f2bf(p3);
            float rsum = p0 + p1 + p2 + p3;
            rsum += __shfl_xor(rsum, 1);
            rsum += __shfl_xor(rsum, 2);
            rsum += __shfl_xor(rsum, 4);
            rsum += __shfl_xor(rsum, 8);
            l_i[reg] += rsum;
        }

        // ---- PV: 16 MFMAs/wave (own wave's P strip, no barrier needed) ----
        const char* Pwb = (const char*)Pw;
        __builtin_amdgcn_s_setprio(1);
        #pragma unroll
        for (int kb = 0; kb < 2; ++kb) {
            const bf16x8 pa = *(const bf16x8*)(Pwb + l15 * 128 +
                                 ((kb * 64 + l4 * 16) ^ ((l15 & 7) << 4)));
            #pragma unroll
            for (int n = 0; n < 8; ++n) {
                const int vrow = n * 16 + l15;
                const bf16x8 vb = *(const bf16x8*)((const char*)Vs[cbuf] + vrow * 128 +
                                     ((kb * 64 + l4 * 16) ^ ((vrow & 7) << 4)));
                accO[n] = __builtin_amdgcn_mfma_f32_16x16x32_bf16(pa, vb, accO[n], 0, 0, 0);
            }
        }
        __builtin_amdgcn_s_setprio(0);

        __syncthreads();   // drains stage(t+1) loads; guards buffer reuse
    }

    // ---- epilogue ----
    float invl[4];
    #pragma unroll
    for (int reg = 0; reg < 4; ++reg) invl[reg] = 1.f / l_i[reg];
    #pragma unroll
    for (int n = 0; n < 8; ++n)
        #pragma unroll
        for (int reg = 0; reg < 4; ++reg) {
            const int row = qt * 64 + w * 16 + l4 * 4 + reg;
            Obf[(size_t)row * DQ + h * HD + n * 16 + l15] = f2bf(accO[n][reg] * invl[reg]);
        }
}

// ---------------------------------------------------------------------------
// d_out (fp32): [ out: S*DQ | k_new: NHKV*S*HD | v_new: NHKV*S*HD ]
// d_ws: x_bf 16MB @0 (attn_bf aliases) | wqkv_bf 48MB @16 (wo_bf aliases)
//       qkv_f32 48MB @64 | q_bf 16MB @112 | k_bf 4MB @128 | vT_bf 4MB @132
// ---------------------------------------------------------------------------
extern "C" void kernel_launch(void* const* d_in, const int* in_sizes, int n_in,
                              void* d_out, int out_size, void* d_ws, size_t ws_size,
                              hipStream_t stream)
{
    const float* x    = (const float*)d_in[0];
    const float* freq = (const float*)d_in[1];
    const float* wq   = (const float*)d_in[2];
    const float* wk   = (const float*)d_in[3];
    const float* wv   = (const float*)d_in[4];
    const float* wo   = (const float*)d_in[5];

    float* out  = (float*)d_out;
    float* knew = out + (size_t)S_LEN * DQ;
    float* vnew = knew + (size_t)NHKV * S_LEN * HD;

    char* ws = (char*)d_ws;
    unsigned short* x_bf    = (unsigned short*)(ws);
    unsigned short* attn_bf = (unsigned short*)(ws);               // aliases x_bf (dead after QKV gemm)
    unsigned short* wqkv_bf = (unsigned short*)(ws + (16u << 20));
    unsigned short* wo_bf   = (unsigned short*)(ws + (16u << 20)); // aliases wqkv (dead after QKV gemm)
    float*          qkv_f32 = (float*)(ws + (64u << 20));
    unsigned short* q_bf    = (unsigned short*)(ws + (112u << 20));
    unsigned short* k_bf    = (unsigned short*)(ws + (128u << 20));
    unsigned short* vT_bf   = (unsigned short*)(ws + (132u << 20));

    const dim3 blk(256);

    // bf16 conversions (weights fused into one QKV buffer)
    cvt_bf16<<<2048, blk, 0, stream>>>(x,  x_bf, S_LEN * DMODEL / 8);
    cvt_bf16<<<2048, blk, 0, stream>>>(wq, wqkv_bf, DQ * DMODEL / 8);
    cvt_bf16<<<1024, blk, 0, stream>>>(wk, wqkv_bf + (size_t)DQ * DMODEL, DKV * DMODEL / 8);
    cvt_bf16<<<1024, blk, 0, stream>>>(wv, wqkv_bf + (size_t)(DQ + DKV) * DMODEL, DKV * DMODEL / 8);

    // fused QKV projection: [2048,6144] = x @ [wq;wk;wv]^T
    gemm_bf16<<<dim3(NQKV / BBN, S_LEN / BBM), blk, 0, stream>>>(x_bf, wqkv_bf, qkv_f32, S_LEN, NQKV, DMODEL);

    // wo conversion (reuses wqkv slot; executes after QKV gemm, same stream)
    cvt_bf16<<<2048, blk, 0, stream>>>(wo, wo_bf, DMODEL * DQ / 8);

    // RoPE + layout transforms
    rope_q<<<NHQ * S_LEN * 64 / 256, blk, 0, stream>>>(qkv_f32, freq, q_bf);
    rope_kv<<<NHKV * S_LEN * 64 / 256, blk, 0, stream>>>(qkv_f32, freq, knew, vnew, k_bf);
    transp_v<<<dim3(S_LEN / 64, 2 * NHKV), blk, 0, stream>>>(qkv_f32, vT_bf);

    // flash attention -> attn_bf [s][4096]
    flash_bf16<<<dim3(NHQ, S_LEN / 64), blk, 0, stream>>>(q_bf, k_bf, vT_bf, attn_bf);

    // output projection: out = attn @ wo^T
    gemm_bf16<<<dim3(DMODEL / BBN, S_LEN / BBM), blk, 0, stream>>>(attn_bf, wo_bf, out, S_LEN, DMODEL, DMODEL);
}